// Round 2
// baseline (1010.843 us; speedup 1.0000x reference)
//
#include <hip/hip_runtime.h>

// Masked mean-pool: out[b,d] = sum_s embed[b,s,d]*mask[b,s] / sum_s mask[b,s]
// mask[b,s] = token_ids[b,s] not in {0 (PAD), 101 (CLS), 102 (SEP)}
//
// B=512, S=512, D=768, fp32. Streaming-read bound: 805 MB -> ~128 us floor.
// R2: split S across 8 blocks per batch row to raise occupancy from 6 to
// ~30 waves/CU (outstanding-load starvation was the R1 bottleneck).

constexpr int B = 512;
constexpr int S = 512;
constexpr int D = 768;
constexpr int NV = D / 4;        // 192 float4 columns; block = 192 threads (3 waves)
constexpr int SPLIT = 8;         // S-chunks per batch row
constexpr int SCHUNK = S / SPLIT;  // 64 rows per block

// Stage 1: each block reduces a 64-row chunk of one batch row.
__global__ __launch_bounds__(NV) void partial_kernel(
    const float4* __restrict__ embed,   // [B, S, NV]
    const int* __restrict__ tok,        // [B, S]
    float4* __restrict__ psum,          // [B, SPLIT, NV]
    float* __restrict__ pcnt)           // [B, SPLIT]
{
    const int b = blockIdx.x;
    const int p = blockIdx.y;
    const int t = threadIdx.x;
    const int s0 = p * SCHUNK;

    __shared__ float maskf[SCHUNK];
    if (t < SCHUNK) {
        int id = tok[b * S + s0 + t];
        maskf[t] = (id != 0 && id != 101 && id != 102) ? 1.0f : 0.0f;
    }
    __syncthreads();

    const float4* row = embed + ((size_t)b * S + s0) * NV + t;
    float4 acc = make_float4(0.f, 0.f, 0.f, 0.f);
    float cnt = 0.f;

#pragma unroll 8
    for (int i = 0; i < SCHUNK; ++i) {
        const float m = maskf[i];           // LDS broadcast, conflict-free
        const float4 v = row[(size_t)i * NV];
        cnt += m;
        acc.x = fmaf(v.x, m, acc.x);
        acc.y = fmaf(v.y, m, acc.y);
        acc.z = fmaf(v.z, m, acc.z);
        acc.w = fmaf(v.w, m, acc.w);
    }

    psum[((size_t)b * SPLIT + p) * NV + t] = acc;
    if (t == 0) pcnt[b * SPLIT + p] = cnt;
}

// Stage 2: combine the SPLIT partials and divide by the count.
__global__ __launch_bounds__(NV) void finalize_kernel(
    const float4* __restrict__ psum,    // [B, SPLIT, NV]
    const float* __restrict__ pcnt,     // [B, SPLIT]
    float4* __restrict__ out)           // [B, NV]
{
    const int b = blockIdx.x;
    const int t = threadIdx.x;

    float4 acc = make_float4(0.f, 0.f, 0.f, 0.f);
    float cnt = 0.f;
#pragma unroll
    for (int p = 0; p < SPLIT; ++p) {
        const float4 v = psum[((size_t)b * SPLIT + p) * NV + t];
        acc.x += v.x; acc.y += v.y; acc.z += v.z; acc.w += v.w;
        cnt += pcnt[b * SPLIT + p];     // redundant per-thread; L1-hit broadcast
    }
    const float inv = 1.0f / cnt;
    out[b * NV + t] = make_float4(acc.x * inv, acc.y * inv, acc.z * inv, acc.w * inv);
}

extern "C" void kernel_launch(void* const* d_in, const int* in_sizes, int n_in,
                              void* d_out, int out_size, void* d_ws, size_t ws_size,
                              hipStream_t stream) {
    const float4* embed = (const float4*)d_in[0];
    const int* tok = (const int*)d_in[1];
    float4* out = (float4*)d_out;

    float4* psum = (float4*)d_ws;                       // 512*8*192*16 B = 12.6 MB
    float* pcnt = (float*)((char*)d_ws + (size_t)B * SPLIT * NV * sizeof(float4));

    partial_kernel<<<dim3(B, SPLIT), dim3(NV), 0, stream>>>(embed, tok, psum, pcnt);
    finalize_kernel<<<dim3(B), dim3(NV), 0, stream>>>(psum, pcnt, out);
}